// Round 1
// baseline (5495.399 us; speedup 1.0000x reference)
//
#include <hip/hip_runtime.h>
#include <hip/hip_bf16.h>

// CTRNN: T=512, B=64, I=512, H=1024
// Plan:
//   1) xproj kernel: out[t*B+b][n] = x[t,b,:]·W_in[n,:] + b_in[n] + b_hh[n]   (bf16 MFMA)
//   2) persistent 64-block kernel: 512 recurrence steps with atomic grid barrier.
//      Block g owns H-cols [16g,16g+16): W_hh slice pinned in LDS (bf16).
//      h exchanged via bf16 ring in d_ws; f32 h kept in out[t] (in-place overwrite of xproj).

typedef __attribute__((ext_vector_type(8))) short short8;
typedef __attribute__((ext_vector_type(4))) float f32x4;

#define TT 512
#define BB 64
#define II 512
#define HH 1024
#define NBLK 64

__device__ __forceinline__ short f2bf(float f) {
  unsigned u = __builtin_bit_cast(unsigned, f);
  u += 0x7fffu + ((u >> 16) & 1u);   // RNE
  return (short)(u >> 16);
}

__device__ __forceinline__ void gbar(int* cnt, int target) {
  __syncthreads();
  if (threadIdx.x == 0) {
    __threadfence();  // release: make ring/out stores visible device-wide
    __hip_atomic_fetch_add(cnt, 1, __ATOMIC_RELAXED, __HIP_MEMORY_SCOPE_AGENT);
    while (__hip_atomic_load(cnt, __ATOMIC_RELAXED, __HIP_MEMORY_SCOPE_AGENT) < target) {
      __builtin_amdgcn_s_sleep(1);
    }
    __threadfence();  // acquire: invalidate caches before reading others' ring data
  }
  __syncthreads();
}

// ---------------- xproj: grid (16 nblk, 512 mblk), 256 thr, block tile 64m x 64n
__global__ __launch_bounds__(256) void xproj_kernel(
    const float* __restrict__ x, const float* __restrict__ Win,
    const float* __restrict__ bin, const float* __restrict__ bhh,
    float* __restrict__ out) {
  __shared__ short Wl[64 * 256];  // K staged in halves (256), XOR-swizzled chunks, 32KB
  const int tid = threadIdx.x;
  const int l = tid & 63, w = tid >> 6;
  const int lr = l & 15, lg = l >> 4;
  const int n0 = blockIdx.x * 64;
  const int m0 = blockIdx.y * 64;

  f32x4 acc[4];
  #pragma unroll
  for (int i = 0; i < 4; ++i) acc[i] = (f32x4){0.f, 0.f, 0.f, 0.f};

  const float* arow = x + (size_t)(m0 + w * 16 + lr) * II + lg * 8;

  for (int ks = 0; ks < II; ks += 256) {
    // stage W_in[n0..n0+63][ks..ks+255] -> bf16 LDS, 16B-chunk XOR swizzle
    for (int i = tid; i < 4096; i += 256) {
      int e = i << 2;
      int r = e >> 8;
      int c = e & 255;
      float4 v = *(const float4*)(Win + (size_t)(n0 + r) * II + ks + c);
      int c8 = c >> 3;
      int dst = r * 256 + ((c8 ^ (r & 7)) << 3) + (c & 7);
      Wl[dst + 0] = f2bf(v.x); Wl[dst + 1] = f2bf(v.y);
      Wl[dst + 2] = f2bf(v.z); Wl[dst + 3] = f2bf(v.w);
    }
    __syncthreads();
    #pragma unroll
    for (int k0 = 0; k0 < 256; k0 += 32) {
      float4 a0 = *(const float4*)(arow + ks + k0);
      float4 a1 = *(const float4*)(arow + ks + k0 + 4);
      short8 af;
      af[0] = f2bf(a0.x); af[1] = f2bf(a0.y); af[2] = f2bf(a0.z); af[3] = f2bf(a0.w);
      af[4] = f2bf(a1.x); af[5] = f2bf(a1.y); af[6] = f2bf(a1.z); af[7] = f2bf(a1.w);
      int kc = (k0 >> 3) + lg;
      #pragma unroll
      for (int ns = 0; ns < 4; ++ns) {
        int r = ns * 16 + lr;
        short8 bf = *(const short8*)(&Wl[r * 256 + (((kc) ^ (r & 7)) << 3)]);
        acc[ns] = __builtin_amdgcn_mfma_f32_16x16x32_bf16(af, bf, acc[ns], 0, 0, 0);
      }
    }
    __syncthreads();
  }

  #pragma unroll
  for (int ns = 0; ns < 4; ++ns) {
    int n = n0 + ns * 16 + lr;
    float bias = bin[n] + bhh[n];
    #pragma unroll
    for (int j = 0; j < 4; ++j) {
      int m = m0 + w * 16 + lg * 4 + j;
      out[(size_t)m * HH + n] = acc[ns][j] + bias;
    }
  }
}

// ---------------- persistent recurrence: 64 blocks x 256 thr
__global__ __launch_bounds__(256) void rnn_persist(
    const float* __restrict__ h0, const float* __restrict__ Whh,
    float* __restrict__ out, short* __restrict__ ring0,
    short* __restrict__ ring1, int* __restrict__ cnt) {
  __shared__ short Wl[16 * 1032];  // 16 rows x 1024 (+8 pad), 33KB
  const int g = blockIdx.x;
  const int tid = threadIdx.x;
  const int l = tid & 63, w = tid >> 6;
  const int lr = l & 15, lg = l >> 4;

  // pin W_hh rows [16g, 16g+16) in LDS as bf16
  for (int i = tid; i < 4096; i += 256) {
    int e = i << 2;
    int r = e >> 10, c = e & 1023;
    float4 v = *(const float4*)(Whh + (size_t)(g * 16 + r) * HH + c);
    int dst = r * 1032 + c;
    Wl[dst + 0] = f2bf(v.x); Wl[dst + 1] = f2bf(v.y);
    Wl[dst + 2] = f2bf(v.z); Wl[dst + 3] = f2bf(v.w);
  }
  // init ring0: block g converts h0 row g (1024 elems)
  {
    int idx = g * HH + (tid << 2);
    float4 v = *(const float4*)(h0 + idx);
    ring0[idx + 0] = f2bf(v.x); ring0[idx + 1] = f2bf(v.y);
    ring0[idx + 2] = f2bf(v.z); ring0[idx + 3] = f2bf(v.w);
  }
  gbar(cnt, NBLK);  // epoch 0: ring0 ready everywhere

  short* rc = ring0;
  short* rn = ring1;
  for (int t = 0; t < TT; ++t) {
    f32x4 a0 = {0.f,0.f,0.f,0.f}, a1 = {0.f,0.f,0.f,0.f},
          a2 = {0.f,0.f,0.f,0.f}, a3 = {0.f,0.f,0.f,0.f};
    const short* ar = rc + (w * 16 + lr) * HH + lg * 8;
    const short* br = &Wl[lr * 1032 + lg * 8];
    #pragma unroll
    for (int k0 = 0; k0 < HH; k0 += 128) {
      a0 = __builtin_amdgcn_mfma_f32_16x16x32_bf16(
          *(const short8*)(ar + k0), *(const short8*)(br + k0), a0, 0, 0, 0);
      a1 = __builtin_amdgcn_mfma_f32_16x16x32_bf16(
          *(const short8*)(ar + k0 + 32), *(const short8*)(br + k0 + 32), a1, 0, 0, 0);
      a2 = __builtin_amdgcn_mfma_f32_16x16x32_bf16(
          *(const short8*)(ar + k0 + 64), *(const short8*)(br + k0 + 64), a2, 0, 0, 0);
      a3 = __builtin_amdgcn_mfma_f32_16x16x32_bf16(
          *(const short8*)(ar + k0 + 96), *(const short8*)(br + k0 + 96), a3, 0, 0, 0);
    }
    f32x4 acc = (a0 + a1) + (a2 + a3);

    float* outt = out + (size_t)t * (BB * HH);
    const float* hp = t ? (outt - BB * HH) : h0;
    #pragma unroll
    for (int j = 0; j < 4; ++j) {
      int row = w * 16 + lg * 4 + j;
      int n = g * 16 + lr;
      int idx = row * HH + n;
      float pre = acc[j] + outt[idx];             // xp (+b_in+b_hh) staged in out
      float s = 1.f / (1.f + __expf(-pre));
      float hn = 0.8f * hp[idx] + 0.2f * s;       // ONE_MINUS_ALPHA, ALPHA, GAIN=1
      outt[idx] = hn;
      rn[idx] = f2bf(hn);
      if (t == TT - 1) out[(size_t)TT * BB * HH + idx] = hn;  // h_last
    }
    gbar(cnt, NBLK * (t + 2));
    short* tmp = rc; rc = rn; rn = tmp;
  }
}

extern "C" void kernel_launch(void* const* d_in, const int* in_sizes, int n_in,
                              void* d_out, int out_size, void* d_ws, size_t ws_size,
                              hipStream_t stream) {
  const float* x   = (const float*)d_in[0];
  const float* h0  = (const float*)d_in[1];
  const float* Win = (const float*)d_in[2];
  const float* bin = (const float*)d_in[3];
  const float* Whh = (const float*)d_in[4];
  const float* bhh = (const float*)d_in[5];
  float* out = (float*)d_out;

  int* cnt = (int*)d_ws;
  short* ring0 = (short*)((char*)d_ws + 256);
  short* ring1 = ring0 + BB * HH;

  hipMemsetAsync(d_ws, 0, 256, stream);  // zero barrier counter each call
  xproj_kernel<<<dim3(16, 512), 256, 0, stream>>>(x, Win, bin, bhh, out);
  rnn_persist<<<dim3(NBLK), 256, 0, stream>>>(h0, Whh, out, ring0, ring1, cnt);
}

// Round 2
// 3610.604 us; speedup vs baseline: 1.5220x; 1.5220x over previous
//
#include <hip/hip_runtime.h>
#include <hip/hip_bf16.h>

// CTRNN: T=512, B=64, I=512, H=1024
//   1) xproj kernel: out[t*B+b][n] = x[t,b,:]·W_in[n,:] + b_in[n] + b_hh[n]   (bf16 MFMA)
//   2) persistent 64-block kernel, fence-free flag barrier:
//      - cross-block data (bf16 h ring) written via relaxed-AGENT atomic 8B stores
//        (write-through sc0 sc1) and read via inline-asm global_load_dwordx4 sc0 sc1.
//      - per-block flag + wave0 poll replaces counter-RMW + threadfence.
//      - block-private data (out, h chain, W_hh LDS) stays on plain ops, L2-warm.

typedef __attribute__((ext_vector_type(8))) short short8;
typedef __attribute__((ext_vector_type(4))) float f32x4;

#define TT 512
#define BB 64
#define II 512
#define HH 1024
#define NBLK 64

__device__ __forceinline__ short f2bf(float f) {
  unsigned u = __builtin_bit_cast(unsigned, f);
  u += 0x7fffu + ((u >> 16) & 1u);   // RNE
  return (short)(u >> 16);
}

// ---------------- xproj: grid (16 nblk, 512 mblk), 256 thr, block tile 64m x 64n
__global__ __launch_bounds__(256) void xproj_kernel(
    const float* __restrict__ x, const float* __restrict__ Win,
    const float* __restrict__ bin, const float* __restrict__ bhh,
    float* __restrict__ out) {
  __shared__ short Wl[64 * 256];  // K staged in halves (256), XOR-swizzled chunks, 32KB
  const int tid = threadIdx.x;
  const int l = tid & 63, w = tid >> 6;
  const int lr = l & 15, lg = l >> 4;
  const int n0 = blockIdx.x * 64;
  const int m0 = blockIdx.y * 64;

  f32x4 acc[4];
  #pragma unroll
  for (int i = 0; i < 4; ++i) acc[i] = (f32x4){0.f, 0.f, 0.f, 0.f};

  const float* arow = x + (size_t)(m0 + w * 16 + lr) * II + lg * 8;

  for (int ks = 0; ks < II; ks += 256) {
    for (int i = tid; i < 4096; i += 256) {
      int e = i << 2;
      int r = e >> 8;
      int c = e & 255;
      float4 v = *(const float4*)(Win + (size_t)(n0 + r) * II + ks + c);
      int c8 = c >> 3;
      int dst = r * 256 + ((c8 ^ (r & 7)) << 3) + (c & 7);
      Wl[dst + 0] = f2bf(v.x); Wl[dst + 1] = f2bf(v.y);
      Wl[dst + 2] = f2bf(v.z); Wl[dst + 3] = f2bf(v.w);
    }
    __syncthreads();
    #pragma unroll
    for (int k0 = 0; k0 < 256; k0 += 32) {
      float4 a0 = *(const float4*)(arow + ks + k0);
      float4 a1 = *(const float4*)(arow + ks + k0 + 4);
      short8 af;
      af[0] = f2bf(a0.x); af[1] = f2bf(a0.y); af[2] = f2bf(a0.z); af[3] = f2bf(a0.w);
      af[4] = f2bf(a1.x); af[5] = f2bf(a1.y); af[6] = f2bf(a1.z); af[7] = f2bf(a1.w);
      int kc = (k0 >> 3) + lg;
      #pragma unroll
      for (int ns = 0; ns < 4; ++ns) {
        int r = ns * 16 + lr;
        short8 bf = *(const short8*)(&Wl[r * 256 + (((kc) ^ (r & 7)) << 3)]);
        acc[ns] = __builtin_amdgcn_mfma_f32_16x16x32_bf16(af, bf, acc[ns], 0, 0, 0);
      }
    }
    __syncthreads();
  }

  #pragma unroll
  for (int ns = 0; ns < 4; ++ns) {
    int n = n0 + ns * 16 + lr;
    float bias = bin[n] + bhh[n];
    #pragma unroll
    for (int j = 0; j < 4; ++j) {
      int m = m0 + w * 16 + lg * 4 + j;
      out[(size_t)m * HH + n] = acc[ns][j] + bias;
    }
  }
}

// ---------------- persistent recurrence: 64 blocks x 256 thr, fence-free
__global__ __launch_bounds__(256) void rnn_persist(
    const float* __restrict__ h0, const float* __restrict__ Whh,
    float* __restrict__ out, short* __restrict__ ring0,
    short* __restrict__ ring1, int* __restrict__ flags) {
  __shared__ short Wl[16 * 1024];  // K-major: fragment(kc, r) at (kc*16 + r)*8, 32KB, conflict-free
  __shared__ short Lh[BB * 16];    // epilogue bounce [row][col-in-block], 2KB
  const int g = blockIdx.x;
  const int tid = threadIdx.x;
  const int l = tid & 63, w = tid >> 6;
  const int lr = l & 15, lg = l >> 4;

  // pin W_hh rows [16g, 16g+16) in LDS, K-major bf16
  for (int i = tid; i < 4096; i += 256) {
    int r = i >> 8;
    int c = (i & 255) * 4;
    float4 v = *(const float4*)(Whh + (size_t)(g * 16 + r) * HH + c);
    int kc = c >> 3, c7 = c & 7;
    short* d = &Wl[(kc * 16 + r) * 8 + c7];
    d[0] = f2bf(v.x); d[1] = f2bf(v.y); d[2] = f2bf(v.z); d[3] = f2bf(v.w);
  }
  // init ring0: block g converts h0 batch-row g (1024 elems) via write-through 8B stores
  {
    float4 v = *(const float4*)(h0 + (size_t)g * HH + tid * 4);
    unsigned long long u =
        (unsigned long long)(unsigned short)f2bf(v.x)
      | ((unsigned long long)(unsigned short)f2bf(v.y) << 16)
      | ((unsigned long long)(unsigned short)f2bf(v.z) << 32)
      | ((unsigned long long)(unsigned short)f2bf(v.w) << 48);
    __hip_atomic_store((unsigned long long*)(ring0 + (size_t)g * HH) + tid, u,
                       __ATOMIC_RELAXED, __HIP_MEMORY_SCOPE_AGENT);
  }
  __syncthreads();  // drains vmcnt: ring stores acked at coherence point
  if (tid == 0)
    __hip_atomic_store(&flags[g], 1, __ATOMIC_RELAXED, __HIP_MEMORY_SCOPE_AGENT);
  if (w == 0) {
    while (!__all(__hip_atomic_load(&flags[l], __ATOMIC_RELAXED,
                                    __HIP_MEMORY_SCOPE_AGENT) >= 1))
      __builtin_amdgcn_s_sleep(1);
  }
  __syncthreads();

  short* rc = ring0;
  short* rn = ring1;
  for (int t = 0; t < TT; ++t) {
    const short* ar = rc + (size_t)(w * 16 + lr) * HH + lg * 8;
    float* outt = out + (size_t)t * (BB * HH);
    const float* hp = t ? (outt - BB * HH) : h0;

    // issue all 32 A-fragment coherent loads (16B each, offsets 0..1984)
    int4 fa[32];
#define LDA(I) asm volatile("global_load_dwordx4 %0, %1, off offset:%2 sc0 sc1" \
                            : "=v"(fa[I]) : "v"(ar), "n"((I) * 64))
    LDA(0);  LDA(1);  LDA(2);  LDA(3);  LDA(4);  LDA(5);  LDA(6);  LDA(7);
    LDA(8);  LDA(9);  LDA(10); LDA(11); LDA(12); LDA(13); LDA(14); LDA(15);
    LDA(16); LDA(17); LDA(18); LDA(19); LDA(20); LDA(21); LDA(22); LDA(23);
    LDA(24); LDA(25); LDA(26); LDA(27); LDA(28); LDA(29); LDA(30); LDA(31);
#undef LDA

    // prefetch block-private epilogue inputs (plain loads, overlap with A drain)
    float xp[4], hpre[4];
    #pragma unroll
    for (int j = 0; j < 4; ++j) {
      int idx = (w * 16 + lg * 4 + j) * HH + g * 16 + lr;
      xp[j] = outt[idx];
      hpre[j] = hp[idx];
    }

    asm volatile("s_waitcnt vmcnt(0)" ::: "memory");
    __builtin_amdgcn_sched_barrier(0);

    f32x4 a0 = {0.f,0.f,0.f,0.f}, a1 = {0.f,0.f,0.f,0.f},
          a2 = {0.f,0.f,0.f,0.f}, a3 = {0.f,0.f,0.f,0.f};
    const short* bW = &Wl[lg * 128 + lr * 8];
    #pragma unroll
    for (int i = 0; i < 32; i += 4) {
      a0 = __builtin_amdgcn_mfma_f32_16x16x32_bf16(
          __builtin_bit_cast(short8, fa[i]),     *(const short8*)(bW + i * 512),       a0, 0, 0, 0);
      a1 = __builtin_amdgcn_mfma_f32_16x16x32_bf16(
          __builtin_bit_cast(short8, fa[i + 1]), *(const short8*)(bW + (i + 1) * 512), a1, 0, 0, 0);
      a2 = __builtin_amdgcn_mfma_f32_16x16x32_bf16(
          __builtin_bit_cast(short8, fa[i + 2]), *(const short8*)(bW + (i + 2) * 512), a2, 0, 0, 0);
      a3 = __builtin_amdgcn_mfma_f32_16x16x32_bf16(
          __builtin_bit_cast(short8, fa[i + 3]), *(const short8*)(bW + (i + 3) * 512), a3, 0, 0, 0);
    }
    f32x4 s4 = (a0 + a1) + (a2 + a3);

    #pragma unroll
    for (int j = 0; j < 4; ++j) {
      int row = w * 16 + lg * 4 + j;
      int idx = row * HH + g * 16 + lr;
      float pre = s4[j] + xp[j];
      float s = 1.f / (1.f + __expf(-pre));
      float hn = 0.8f * hpre[j] + 0.2f * s;   // ONE_MINUS_ALPHA, ALPHA, GAIN=1
      outt[idx] = hn;
      Lh[row * 16 + lr] = f2bf(hn);
      if (t == TT - 1) out[(size_t)TT * BB * HH + idx] = hn;  // h_last
    }
    __syncthreads();
    {
      // pack 4 cols x 1 row per thread, one write-through 8B store each
      int r = tid >> 2, q = tid & 3;
      unsigned long long u = *(const unsigned long long*)&Lh[r * 16 + q * 4];
      __hip_atomic_store((unsigned long long*)(rn + (size_t)r * HH + g * 16) + q, u,
                         __ATOMIC_RELAXED, __HIP_MEMORY_SCOPE_AGENT);
    }
    __syncthreads();  // drains each wave's vmcnt: ring stores acked
    if (tid == 0)
      __hip_atomic_store(&flags[g], t + 2, __ATOMIC_RELAXED, __HIP_MEMORY_SCOPE_AGENT);
    if (w == 0) {
      int target = t + 2;
      while (!__all(__hip_atomic_load(&flags[l], __ATOMIC_RELAXED,
                                      __HIP_MEMORY_SCOPE_AGENT) >= target))
        __builtin_amdgcn_s_sleep(1);
    }
    __syncthreads();
    short* tmp = rc; rc = rn; rn = tmp;
  }
}

extern "C" void kernel_launch(void* const* d_in, const int* in_sizes, int n_in,
                              void* d_out, int out_size, void* d_ws, size_t ws_size,
                              hipStream_t stream) {
  const float* x   = (const float*)d_in[0];
  const float* h0  = (const float*)d_in[1];
  const float* Win = (const float*)d_in[2];
  const float* bin = (const float*)d_in[3];
  const float* Whh = (const float*)d_in[4];
  const float* bhh = (const float*)d_in[5];
  float* out = (float*)d_out;

  int* flags = (int*)d_ws;                         // 64 ints, memset to 0
  short* ring0 = (short*)((char*)d_ws + 256);
  short* ring1 = ring0 + BB * HH;

  hipMemsetAsync(d_ws, 0, 256, stream);
  xproj_kernel<<<dim3(16, 512), 256, 0, stream>>>(x, Win, bin, bhh, out);
  rnn_persist<<<dim3(NBLK), 256, 0, stream>>>(h0, Whh, out, ring0, ring1, flags);
}

// Round 4
// 1853.709 us; speedup vs baseline: 2.9645x; 1.9478x over previous
//
#include <hip/hip_runtime.h>
#include <hip/hip_bf16.h>

// CTRNN: T=512, B=64, I=512, H=1024
//   1) xproj: out[t*B+b][n] = x[t,b,:]·W_in[n,:] + b_in[n] + b_hh[n]   (bf16 MFMA)
//   2) rnn_persist: 64 blocks = 4 batch-groups (r, 16 rows) x 16 col-groups (g, 64 cols).
//      W_hh slice (64 cols x 1024 K) pinned in LDS (128 KB); waves K-split (256 each);
//      partials reduced via LDS. h exchanged per batch-group through a fragment-tiled
//      bf16 ring (write-through relaxed-agent stores / sc0 sc1 loads); per-producer flags.

typedef __attribute__((ext_vector_type(8))) short short8;
typedef __attribute__((ext_vector_type(4))) float f32x4;
typedef unsigned long long ull;

#define TT 512
#define BB 64
#define II 512
#define HH 1024

__device__ __forceinline__ short f2bf(float f) {
  unsigned u = __builtin_bit_cast(unsigned, f);
  u += 0x7fffu + ((u >> 16) & 1u);   // RNE
  return (short)(u >> 16);
}

// ---------------- xproj: grid (16 nblk, 512 mblk), 256 thr, block tile 64m x 64n
__global__ __launch_bounds__(256) void xproj_kernel(
    const float* __restrict__ x, const float* __restrict__ Win,
    const float* __restrict__ bin, const float* __restrict__ bhh,
    float* __restrict__ out) {
  __shared__ short Wl[64 * 256];
  const int tid = threadIdx.x;
  const int l = tid & 63, w = tid >> 6;
  const int lr = l & 15, lg = l >> 4;
  const int n0 = blockIdx.x * 64;
  const int m0 = blockIdx.y * 64;

  f32x4 acc[4];
  #pragma unroll
  for (int i = 0; i < 4; ++i) acc[i] = (f32x4){0.f, 0.f, 0.f, 0.f};

  const float* arow = x + (size_t)(m0 + w * 16 + lr) * II + lg * 8;

  for (int ks = 0; ks < II; ks += 256) {
    for (int i = tid; i < 4096; i += 256) {
      int e = i << 2;
      int r = e >> 8;
      int c = e & 255;
      float4 v = *(const float4*)(Win + (size_t)(n0 + r) * II + ks + c);
      int c8 = c >> 3;
      int dst = r * 256 + ((c8 ^ (r & 7)) << 3) + (c & 7);
      Wl[dst + 0] = f2bf(v.x); Wl[dst + 1] = f2bf(v.y);
      Wl[dst + 2] = f2bf(v.z); Wl[dst + 3] = f2bf(v.w);
    }
    __syncthreads();
    #pragma unroll
    for (int k0 = 0; k0 < 256; k0 += 32) {
      float4 a0 = *(const float4*)(arow + ks + k0);
      float4 a1 = *(const float4*)(arow + ks + k0 + 4);
      short8 af;
      af[0] = f2bf(a0.x); af[1] = f2bf(a0.y); af[2] = f2bf(a0.z); af[3] = f2bf(a0.w);
      af[4] = f2bf(a1.x); af[5] = f2bf(a1.y); af[6] = f2bf(a1.z); af[7] = f2bf(a1.w);
      int kc = (k0 >> 3) + lg;
      #pragma unroll
      for (int ns = 0; ns < 4; ++ns) {
        int r = ns * 16 + lr;
        short8 bf = *(const short8*)(&Wl[r * 256 + (((kc) ^ (r & 7)) << 3)]);
        acc[ns] = __builtin_amdgcn_mfma_f32_16x16x32_bf16(af, bf, acc[ns], 0, 0, 0);
      }
    }
    __syncthreads();
  }

  #pragma unroll
  for (int ns = 0; ns < 4; ++ns) {
    int n = n0 + ns * 16 + lr;
    float bias = bin[n] + bhh[n];
    #pragma unroll
    for (int j = 0; j < 4; ++j) {
      int m = m0 + w * 16 + lg * 4 + j;
      out[(size_t)m * HH + n] = acc[ns][j] + bias;
    }
  }
}

// ---------------- persistent recurrence
// ring bf16 layout: [r][kc][row16][8] shorts, kc = k/8 in [0,128); 128 KB per ring.
__global__ __launch_bounds__(256) void rnn_persist(
    const float* __restrict__ h0, const float* __restrict__ Whh,
    float* __restrict__ out, short* __restrict__ ring0,
    short* __restrict__ ring1, int* __restrict__ flags) {
  __shared__ short Wl[64 * 1024];    // fragment (kc,n) at (kc*64+n)*8 shorts, 128 KB
  __shared__ float Pr[4 * 16 * 64];  // per-wave K-partials, 16 KB

  const int bid = blockIdx.x;
  const int r = bid & 3, g = bid >> 2;
  const int tid = threadIdx.x;
  const int l = tid & 63, w = tid >> 6;
  const int lr = l & 15, lg = l >> 4;

  // stage W_hh rows (output cols) [64g, 64g+64), K-major bf16 fragments
  const int n0 = g * 64;
  for (int j = 0; j < 32; ++j) {
    int c = j * 256 + tid;           // chunk: kc = c&127, n = c>>7
    int kc = c & 127, n = c >> 7;
    const float* src = Whh + (size_t)(n0 + n) * HH + kc * 8;
    float4 v0 = *(const float4*)src;
    float4 v1 = *(const float4*)(src + 4);
    short* d = Wl + (((size_t)kc * 64 + n) << 3);
    d[0] = f2bf(v0.x); d[1] = f2bf(v0.y); d[2] = f2bf(v0.z); d[3] = f2bf(v0.w);
    d[4] = f2bf(v1.x); d[5] = f2bf(v1.y); d[6] = f2bf(v1.z); d[7] = f2bf(v1.w);
  }

  // epilogue thread tile: row brow (0..15), cols c0..c0+3 within block chunk
  const int brow = tid >> 4;
  const int c0 = (tid & 15) * 4;
  const size_t oidx = (size_t)(16 * r + brow) * HH + n0 + c0;
  const size_t ringoff =
      (((size_t)(r * 128 + 8 * g + (c0 >> 3)) * 16 + brow) << 3) + (c0 & 7);

  // init ring0 from h0
  {
    float4 v = *(const float4*)(h0 + oidx);
    ull u = (ull)(unsigned short)f2bf(v.x)
          | ((ull)(unsigned short)f2bf(v.y) << 16)
          | ((ull)(unsigned short)f2bf(v.z) << 32)
          | ((ull)(unsigned short)f2bf(v.w) << 48);
    __hip_atomic_store((ull*)(ring0 + ringoff), u,
                       __ATOMIC_RELAXED, __HIP_MEMORY_SCOPE_AGENT);
  }
  __syncthreads();  // drains vmcnt: init ring stores at coherence point
  if (tid == 0)
    __hip_atomic_store(&flags[bid], 1, __ATOMIC_RELAXED, __HIP_MEMORY_SCOPE_AGENT);

  // wave w consumes k in [256w, 256w+256) -> producers g' = 4w + (l&3)
  const int fidx = 16 * w + 4 * (l & 3) + r;
  const short* bW = Wl + ((((size_t)(32 * w + lg)) * 64 + lr) << 3);

  for (int t = 0; t < TT; ++t) {
    short* rc = (t & 1) ? ring1 : ring0;
    short* rn = (t & 1) ? ring0 : ring1;
    float* outt = out + (size_t)t * (BB * HH);
    const float* hp = t ? outt - BB * HH : h0;

    // block-private epilogue inputs (issue before poll to hide latency)
    float4 xpv = *(const float4*)(outt + oidx);  // x_proj (+biases) staged in out
    float4 hpv = *(const float4*)(hp + oidx);    // our own h from last step

    // wait for this wave's 4 producers to have published h_t
    {
      int target = t + 1;
      while (!__all(__hip_atomic_load(&flags[fidx], __ATOMIC_RELAXED,
                                      __HIP_MEMORY_SCOPE_AGENT) >= target))
        __builtin_amdgcn_s_sleep(1);
    }

    // 8 contiguous 1KB-per-wave coherent A loads (this wave's K-slice)
    // 13-bit signed imm offset (max 4095): use two bases 4KB apart.
    const short* ar = rc + ((((size_t)(r * 128 + 32 * w + lg)) * 16 + lr) << 3);
    const short* ar2 = ar + 2048;  // +4096 bytes
    int4 fa[8];
#define LDA(I, BASE, OFF) \
    asm volatile("global_load_dwordx4 %0, %1, off offset:%2 sc0 sc1" \
                 : "=v"(fa[I]) : "v"(BASE), "n"(OFF))
    LDA(0, ar, 0); LDA(1, ar, 1024); LDA(2, ar, 2048); LDA(3, ar, 3072);
    LDA(4, ar2, 0); LDA(5, ar2, 1024); LDA(6, ar2, 2048); LDA(7, ar2, 3072);
#undef LDA

    asm volatile("s_waitcnt vmcnt(0)" ::: "memory");
    __builtin_amdgcn_sched_barrier(0);

    f32x4 acc[4];
    acc[0] = acc[1] = acc[2] = acc[3] = (f32x4){0.f, 0.f, 0.f, 0.f};
    #pragma unroll
    for (int i = 0; i < 8; ++i) {
      short8 a = __builtin_bit_cast(short8, fa[i]);
      acc[0] = __builtin_amdgcn_mfma_f32_16x16x32_bf16(
          a, *(const short8*)(bW + i * 2048 + 0),   acc[0], 0, 0, 0);
      acc[1] = __builtin_amdgcn_mfma_f32_16x16x32_bf16(
          a, *(const short8*)(bW + i * 2048 + 128), acc[1], 0, 0, 0);
      acc[2] = __builtin_amdgcn_mfma_f32_16x16x32_bf16(
          a, *(const short8*)(bW + i * 2048 + 256), acc[2], 0, 0, 0);
      acc[3] = __builtin_amdgcn_mfma_f32_16x16x32_bf16(
          a, *(const short8*)(bW + i * 2048 + 384), acc[3], 0, 0, 0);
    }

    // publish K-partials: D row = lg*4+jj (batch), col = nt*16+lr
    float* pw = Pr + w * 1024;
    #pragma unroll
    for (int nt = 0; nt < 4; ++nt) {
      #pragma unroll
      for (int jj = 0; jj < 4; ++jj)
        pw[(lg * 4 + jj) * 64 + nt * 16 + lr] = acc[nt][jj];
    }
    __syncthreads();

    // reduce 4 K-partials + epilogue
    const float* pb = Pr + brow * 64 + c0;
    f32x4 s = *(const f32x4*)(pb)
            + *(const f32x4*)(pb + 1024)
            + *(const f32x4*)(pb + 2048)
            + *(const f32x4*)(pb + 3072);
    f32x4 hn;
    #pragma unroll
    for (int k = 0; k < 4; ++k) {
      float pre = s[k] + ((const float*)&xpv)[k];
      float sg = 1.f / (1.f + __expf(-pre));
      hn[k] = 0.8f * ((const float*)&hpv)[k] + 0.2f * sg;  // 1-ALPHA, ALPHA, GAIN=1
    }
    ull u = (ull)(unsigned short)f2bf(hn[0])
          | ((ull)(unsigned short)f2bf(hn[1]) << 16)
          | ((ull)(unsigned short)f2bf(hn[2]) << 32)
          | ((ull)(unsigned short)f2bf(hn[3]) << 48);
    __hip_atomic_store((ull*)(rn + ringoff), u,
                       __ATOMIC_RELAXED, __HIP_MEMORY_SCOPE_AGENT);
    *(float4*)(outt + oidx) = *(float4*)&hn;
    if (t == TT - 1) *(float4*)(out + (size_t)TT * BB * HH + oidx) = *(float4*)&hn;
    __syncthreads();  // drains vmcnt: ring stores acked at coherence point
    if (tid == 0)
      __hip_atomic_store(&flags[bid], t + 2, __ATOMIC_RELAXED, __HIP_MEMORY_SCOPE_AGENT);
  }
}

extern "C" void kernel_launch(void* const* d_in, const int* in_sizes, int n_in,
                              void* d_out, int out_size, void* d_ws, size_t ws_size,
                              hipStream_t stream) {
  const float* x   = (const float*)d_in[0];
  const float* h0  = (const float*)d_in[1];
  const float* Win = (const float*)d_in[2];
  const float* bin = (const float*)d_in[3];
  const float* Whh = (const float*)d_in[4];
  const float* bhh = (const float*)d_in[5];
  float* out = (float*)d_out;

  int* flags = (int*)d_ws;                       // 64 ints
  short* ring0 = (short*)((char*)d_ws + 256);    // 128 KB
  short* ring1 = ring0 + BB * HH;                // 128 KB

  hipMemsetAsync(d_ws, 0, 256, stream);
  xproj_kernel<<<dim3(16, 512), 256, 0, stream>>>(x, Win, bin, bhh, out);
  rnn_persist<<<dim3(64), 256, 0, stream>>>(h0, Whh, out, ring0, ring1, flags);
}

// Round 8
// 1522.011 us; speedup vs baseline: 3.6106x; 1.2179x over previous
//
#include <hip/hip_runtime.h>
#include <hip/hip_bf16.h>

// CTRNN: T=512, B=64, I=512, H=1024
//   1) xproj: out[t*B+b][n] = x[t,b,:]·W_in[n,:] + b_in[n] + b_hh[n]   (bf16 MFMA)
//   2) rnn_persist: 64 blocks = 4 batch-groups (r) x 16 col-groups (g).
//      W_hh slice (64 cols x 1024 K) pinned in LDS (128 KB); waves K-split (256 each);
//      LDS reduce. h exchanged through a fragment-tiled bf16 ring via relaxed-agent
//      8B stores; per-block FLAGS (proven protocol, rounds 2+4): publish -> vmcnt(0)
//      -> barrier -> flag; consumer polls its own 4 producers' flags then sc0sc1-loads.
//      Own-h carried in registers; next x_proj prefetched behind the flag.

typedef __attribute__((ext_vector_type(8))) short short8;
typedef __attribute__((ext_vector_type(4))) float f32x4;
typedef unsigned long long ull;

#define TT 512
#define BB 64
#define II 512
#define HH 1024

__device__ __forceinline__ short f2bf(float f) {
  unsigned u = __builtin_bit_cast(unsigned, f);
  u += 0x7fffu + ((u >> 16) & 1u);   // RNE
  return (short)(u >> 16);
}

// ---------------- xproj: grid (16 nblk, 512 mblk), 256 thr, block tile 64m x 64n
__global__ __launch_bounds__(256) void xproj_kernel(
    const float* __restrict__ x, const float* __restrict__ Win,
    const float* __restrict__ bin, const float* __restrict__ bhh,
    float* __restrict__ out) {
  __shared__ short Wl[64 * 256];
  const int tid = threadIdx.x;
  const int l = tid & 63, w = tid >> 6;
  const int lr = l & 15, lg = l >> 4;
  const int n0 = blockIdx.x * 64;
  const int m0 = blockIdx.y * 64;

  f32x4 acc[4];
  #pragma unroll
  for (int i = 0; i < 4; ++i) acc[i] = (f32x4){0.f, 0.f, 0.f, 0.f};

  const float* arow = x + (size_t)(m0 + w * 16 + lr) * II + lg * 8;

  for (int ks = 0; ks < II; ks += 256) {
    for (int i = tid; i < 4096; i += 256) {
      int e = i << 2;
      int r = e >> 8;
      int c = e & 255;
      float4 v = *(const float4*)(Win + (size_t)(n0 + r) * II + ks + c);
      int c8 = c >> 3;
      int dst = r * 256 + ((c8 ^ (r & 7)) << 3) + (c & 7);
      Wl[dst + 0] = f2bf(v.x); Wl[dst + 1] = f2bf(v.y);
      Wl[dst + 2] = f2bf(v.z); Wl[dst + 3] = f2bf(v.w);
    }
    __syncthreads();
    #pragma unroll
    for (int k0 = 0; k0 < 256; k0 += 32) {
      float4 a0 = *(const float4*)(arow + ks + k0);
      float4 a1 = *(const float4*)(arow + ks + k0 + 4);
      short8 af;
      af[0] = f2bf(a0.x); af[1] = f2bf(a0.y); af[2] = f2bf(a0.z); af[3] = f2bf(a0.w);
      af[4] = f2bf(a1.x); af[5] = f2bf(a1.y); af[6] = f2bf(a1.z); af[7] = f2bf(a1.w);
      int kc = (k0 >> 3) + lg;
      #pragma unroll
      for (int ns = 0; ns < 4; ++ns) {
        int r = ns * 16 + lr;
        short8 bf = *(const short8*)(&Wl[r * 256 + (((kc) ^ (r & 7)) << 3)]);
        acc[ns] = __builtin_amdgcn_mfma_f32_16x16x32_bf16(af, bf, acc[ns], 0, 0, 0);
      }
    }
    __syncthreads();
  }

  #pragma unroll
  for (int ns = 0; ns < 4; ++ns) {
    int n = n0 + ns * 16 + lr;
    float bias = bin[n] + bhh[n];
    #pragma unroll
    for (int j = 0; j < 4; ++j) {
      int m = m0 + w * 16 + lg * 4 + j;
      out[(size_t)m * HH + n] = acc[ns][j] + bias;
    }
  }
}

// ---------------- persistent recurrence, flag-gated ring (round-4 protocol)
// ring bf16 layout: granule (r*128 + kc)*16 + row16, 8 shorts each; kc = k/8.
__global__ __launch_bounds__(256) void rnn_persist(
    const float* __restrict__ h0, const float* __restrict__ Whh,
    float* __restrict__ out, short* __restrict__ ring0,
    short* __restrict__ ring1, int* __restrict__ flags) {
  __shared__ short Wl[64 * 1024];   // fragment (kc,n) at (kc*64+n)*8 shorts, 128 KB
  __shared__ float Pr[4 * 16 * 68]; // per-wave K-partials, stride 68 (anti-conflict)

  const int bid = blockIdx.x;
  const int r = bid & 3, g = bid >> 2;
  const int tid = threadIdx.x;
  const int l = tid & 63, w = tid >> 6;
  const int lr = l & 15, lg = l >> 4;

  // stage W_hh rows (output cols) [64g, 64g+64), K-major bf16 fragments
  const int n0 = g * 64;
  for (int j = 0; j < 32; ++j) {
    int c = j * 256 + tid;           // c = n*128 + kc
    int kc = c & 127, n = c >> 7;
    const float* src = Whh + (size_t)(n0 + n) * HH + kc * 8;
    float4 v0 = *(const float4*)src;
    float4 v1 = *(const float4*)(src + 4);
    short* d = Wl + (((size_t)kc * 64 + n) << 3);
    d[0] = f2bf(v0.x); d[1] = f2bf(v0.y); d[2] = f2bf(v0.z); d[3] = f2bf(v0.w);
    d[4] = f2bf(v1.x); d[5] = f2bf(v1.y); d[6] = f2bf(v1.z); d[7] = f2bf(v1.w);
  }

  // epilogue thread tile: row brow (0..15), cols c0..c0+3 within block chunk
  const int brow = tid >> 4;
  const int c0 = (tid & 15) * 4;
  const size_t oidx = (size_t)(16 * r + brow) * HH + n0 + c0;
  const size_t ringoff =
      (((size_t)(r * 128 + 8 * g + (c0 >> 3)) * 16 + brow) << 3) + (c0 & 7);

  // init ring0 from h0; carry own h in register
  f32x4 hpv;
  {
    float4 v = *(const float4*)(h0 + oidx);
    hpv[0] = v.x; hpv[1] = v.y; hpv[2] = v.z; hpv[3] = v.w;
    ull u = (ull)(unsigned short)f2bf(v.x)
          | ((ull)(unsigned short)f2bf(v.y) << 16)
          | ((ull)(unsigned short)f2bf(v.z) << 32)
          | ((ull)(unsigned short)f2bf(v.w) << 48);
    __hip_atomic_store((ull*)(ring0 + ringoff), u,
                       __ATOMIC_RELAXED, __HIP_MEMORY_SCOPE_AGENT);
  }
  // prefetch x_proj[0] (plain load)
  f32x4 xpv;
  {
    float4 v = *(const float4*)(out + oidx);
    xpv[0] = v.x; xpv[1] = v.y; xpv[2] = v.z; xpv[3] = v.w;
  }
  __syncthreads();  // drains vmcnt: init ring stores at coherence point
  if (tid == 0)
    __hip_atomic_store(&flags[bid], 1, __ATOMIC_RELAXED, __HIP_MEMORY_SCOPE_AGENT);

  // wave w consumes kc in [32w, 32w+32) -> producer blocks bid' = 16w + 4(l&3) + r
  const int fidx = 16 * w + 4 * (l & 3) + r;
  const short* bW = Wl + ((((size_t)(32 * w + lg)) * 64 + lr) << 3);
  const size_t abase = ((((size_t)(r * 128 + 32 * w + lg)) * 16 + lr) << 3);

  for (int t = 0; t < TT; ++t) {
    short* rc = (t & 1) ? ring1 : ring0;
    short* rn = (t & 1) ? ring0 : ring1;
    float* outt = out + (size_t)t * (BB * HH);

    // 1. wait for this wave's 4 producers to have published h_t
    {
      int target = t + 1;
      while (!__all(__hip_atomic_load(&flags[fidx], __ATOMIC_RELAXED,
                                      __HIP_MEMORY_SCOPE_AGENT) >= target))
        __builtin_amdgcn_s_sleep(1);
    }

    // 2. coherent A loads of this wave's K-slice (kc = 32w+lg+4i)
    const short* ar = rc + abase;
    const short* ar2 = ar + 2048;  // +4096 bytes
    int4 fa[8];
#define LDA(I, BASE, OFF) \
    asm volatile("global_load_dwordx4 %0, %1, off offset:%2 sc0 sc1" \
                 : "=v"(fa[I]) : "v"(BASE), "n"(OFF))
    LDA(0, ar, 0); LDA(1, ar, 1024); LDA(2, ar, 2048); LDA(3, ar, 3072);
    LDA(4, ar2, 0); LDA(5, ar2, 1024); LDA(6, ar2, 2048); LDA(7, ar2, 3072);
#undef LDA
    asm volatile("s_waitcnt vmcnt(0)" ::: "memory");
    __builtin_amdgcn_sched_barrier(0);

    // 3. MFMA over this wave's 32 kc slices
    f32x4 acc[4];
    acc[0] = acc[1] = acc[2] = acc[3] = (f32x4){0.f, 0.f, 0.f, 0.f};
    #pragma unroll
    for (int i = 0; i < 8; ++i) {
      short8 a = __builtin_bit_cast(short8, fa[i]);
      acc[0] = __builtin_amdgcn_mfma_f32_16x16x32_bf16(
          a, *(const short8*)(bW + i * 2048 + 0),   acc[0], 0, 0, 0);
      acc[1] = __builtin_amdgcn_mfma_f32_16x16x32_bf16(
          a, *(const short8*)(bW + i * 2048 + 128), acc[1], 0, 0, 0);
      acc[2] = __builtin_amdgcn_mfma_f32_16x16x32_bf16(
          a, *(const short8*)(bW + i * 2048 + 256), acc[2], 0, 0, 0);
      acc[3] = __builtin_amdgcn_mfma_f32_16x16x32_bf16(
          a, *(const short8*)(bW + i * 2048 + 384), acc[3], 0, 0, 0);
    }

    // 4. publish K-partials: D row = lg*4+jj (batch), col = nt*16+lr
    float* pw = Pr + w * 1088;
    #pragma unroll
    for (int nt = 0; nt < 4; ++nt) {
      #pragma unroll
      for (int jj = 0; jj < 4; ++jj)
        pw[(lg * 4 + jj) * 68 + nt * 16 + lr] = acc[nt][jj];
    }
    __syncthreads();

    // 5. reduce 4 K-partials + sigmoid update (xpv, hpv carried in regs)
    const float* pb = Pr + brow * 68 + c0;
    f32x4 s = *(const f32x4*)(pb)
            + *(const f32x4*)(pb + 1088)
            + *(const f32x4*)(pb + 2176)
            + *(const f32x4*)(pb + 3264);
    f32x4 hn;
    #pragma unroll
    for (int k = 0; k < 4; ++k) {
      float pre = s[k] + xpv[k];
      float sg = 1.f / (1.f + __expf(-pre));
      hn[k] = 0.8f * hpv[k] + 0.2f * sg;  // 1-ALPHA, ALPHA, GAIN=1
    }

    // 6. publish h_{t+1} to the ring (one 8B relaxed-agent store per thread)
    {
      ull u = (ull)(unsigned short)f2bf(hn[0])
            | ((ull)(unsigned short)f2bf(hn[1]) << 16)
            | ((ull)(unsigned short)f2bf(hn[2]) << 32)
            | ((ull)(unsigned short)f2bf(hn[3]) << 48);
      __hip_atomic_store((ull*)(rn + ringoff), u,
                         __ATOMIC_RELAXED, __HIP_MEMORY_SCOPE_AGENT);
    }
    // 7. drain ring stores, block barrier (also Pr reuse guard), raise flag
    asm volatile("s_waitcnt vmcnt(0)" ::: "memory");
    __syncthreads();
    if (tid == 0)
      __hip_atomic_store(&flags[bid], t + 2, __ATOMIC_RELAXED, __HIP_MEMORY_SCOPE_AGENT);

    // 8. non-critical tail (hidden behind other blocks' consumption):
    //    write h_{t+1} to out, prefetch next x_proj, carry hn in register
    *(float4*)(outt + oidx) = *(float4*)&hn;
    if (t == TT - 1) {
      *(float4*)(out + (size_t)TT * BB * HH + oidx) = *(float4*)&hn;
    } else {
      float4 v = *(const float4*)(outt + BB * HH + oidx);
      xpv[0] = v.x; xpv[1] = v.y; xpv[2] = v.z; xpv[3] = v.w;
    }
    hpv = hn;
  }
}

extern "C" void kernel_launch(void* const* d_in, const int* in_sizes, int n_in,
                              void* d_out, int out_size, void* d_ws, size_t ws_size,
                              hipStream_t stream) {
  const float* x   = (const float*)d_in[0];
  const float* h0  = (const float*)d_in[1];
  const float* Win = (const float*)d_in[2];
  const float* bin = (const float*)d_in[3];
  const float* Whh = (const float*)d_in[4];
  const float* bhh = (const float*)d_in[5];
  float* out = (float*)d_out;

  int* flags = (int*)d_ws;                       // 64 ints (256 B)
  short* ring0 = (short*)((char*)d_ws + 256);    // 128 KB
  short* ring1 = ring0 + BB * HH;                // 128 KB (total 262,400 B, proven)

  hipMemsetAsync(d_ws, 0, 256, stream);
  xproj_kernel<<<dim3(16, 512), 256, 0, stream>>>(x, Win, bin, bhh, out);
  rnn_persist<<<dim3(64), 256, 0, stream>>>(h0, Whh, out, ring0, ring1, flags);
}